// Round 4
// baseline (205.870 us; speedup 1.0000x reference)
//
#include <hip/hip_runtime.h>
#include <hip/hip_bf16.h>

typedef unsigned short u16;
typedef unsigned int u32;
typedef short bf16x8 __attribute__((ext_vector_type(8)));
typedef float f32x4 __attribute__((ext_vector_type(4)));
typedef u16 u16x8 __attribute__((ext_vector_type(8)));

#define HID 1024
#define BATCH 4096
#define KTOT 2048       // concat K: [x | h_prev]
#define NT 32           // K tiles of 64
// LDS element-index region bases: [A buf0 | B buf0 | A buf1 | B buf1]
#define A0B 0
#define B0B 16384
#define A1B 32768
#define B1B 49152

__device__ __forceinline__ u16 f2bf(float f) {
  u32 v = __builtin_bit_cast(u32, f);
  u32 r = (v + 0x7fffu + ((v >> 16) & 1u)) >> 16;  // round-nearest-even
  return (u16)r;
}
__device__ __forceinline__ float sigmoid_fast(float x) {
  return 1.0f / (1.0f + __expf(-x));
}
__device__ __forceinline__ float tanh_fast(float x) {
  return 2.0f * sigmoid_fast(2.0f * x) - 1.0f;
}
__device__ __forceinline__ void gl_lds16(const void* g, void* l) {
  __builtin_amdgcn_global_load_lds(
      (const __attribute__((address_space(1))) u32*)g,
      (__attribute__((address_space(3))) u32*)l, 16, 0, 0);
}

// ---------------------------------------------------------------------------
// prep_all: fused prep. Blocks [0,4096) build xh (bf16 [B][2048]); blocks
// [4096,6144) build Bt[n'][k] (bf16, gate-interleaved n') via LDS transpose.
// ---------------------------------------------------------------------------
__global__ __launch_bounds__(256) void prep_all(
    const float* __restrict__ x, const float* __restrict__ hp,
    const float* __restrict__ igx, const float* __restrict__ fgx,
    const float* __restrict__ ogx, const float* __restrict__ cgx,
    const float* __restrict__ igu, const float* __restrict__ fgu,
    const float* __restrict__ ogu, const float* __restrict__ cgu,
    u16* __restrict__ xh, u16* __restrict__ bt) {
  __shared__ u16 lds[64 * 66];
  if (blockIdx.x < 4096) {
    int c = blockIdx.x * 256 + threadIdx.x;  // chunk id, 8 elems each
    int row = c >> 8;
    int col0 = (c & 255) << 3;
    const float* src = (col0 < 1024)
                           ? (x + (size_t)row * 1024 + col0)
                           : (hp + (size_t)row * 1024 + (col0 - 1024));
    f32x4 a = *(const f32x4*)(src);
    f32x4 b = *(const f32x4*)(src + 4);
    u16x8 v;
#pragma unroll
    for (int j = 0; j < 4; ++j) { v[j] = f2bf(a[j]); v[j + 4] = f2bf(b[j]); }
    *(u16x8*)(xh + (size_t)row * KTOT + col0) = v;
    return;
  }
  // ---- weight transpose: n' = (h/16)*64 + g*16 + (h%16), k = which*1024+ksrc
  const float* srcs[8] = {igx, fgx, ogx, cgx, igu, fgu, ogu, cgu};
  int bid = blockIdx.x - 4096;
  int m = bid >> 8;            // matrix 0..7
  int tile = bid & 255;        // 64x64 tile
  int th = tile & 15, tk = tile >> 4;
  int h0 = th << 6, k0 = tk << 6;
  int g = m & 3, which = m >> 2;
  const float* W = srcs[m] + (size_t)k0 * HID + h0;

  int t = threadIdx.x;
  int r1 = t >> 4;
  int c1 = (t & 15) << 2;
#pragma unroll
  for (int p = 0; p < 4; ++p) {
    int row = (p << 4) + r1;
    f32x4 v = *(const f32x4*)(W + (size_t)row * HID + c1);
    u32 p0 = (u32)f2bf(v[0]) | ((u32)f2bf(v[1]) << 16);
    u32 p1 = (u32)f2bf(v[2]) | ((u32)f2bf(v[3]) << 16);
    u32* d = (u32*)&lds[row * 66 + c1];
    d[0] = p0;
    d[1] = p1;
  }
  __syncthreads();
  int nl = t >> 2;
  int kc = t & 3;
  int row_np = ((h0 >> 4) << 6) + ((nl >> 4) << 6) + (g << 4) + (nl & 15);
  size_t dst = (size_t)row_np * KTOT + (size_t)which * 1024 + k0;
  u16x8 a2, b2;
#pragma unroll
  for (int j = 0; j < 8; ++j) {
    a2[j] = lds[(kc * 8 + j) * 66 + nl];
    b2[j] = lds[(kc * 8 + 32 + j) * 66 + nl];
  }
  *(u16x8*)(&bt[dst + kc * 8]) = a2;
  *(u16x8*)(&bt[dst + kc * 8 + 32]) = b2;
}

// ---------------------------------------------------------------------------
// lstm_gemm: 256x256 tile, 8 waves (2Mx4N), BK=64, 8-phase schedule, counted
// vmcnt (T3+T4), setprio (T5), XOR k-chunk swizzle via pre-swizzled global
// source (T2-equivalent, conflicts=0), T1 XCD block swizzle. 128 KiB LDS
// double buffer. K-loop fully specialized into even/odd tile bodies: every
// stage is a compile-time (region, k-offset) pair — no runtime schedule
// decode, no pointer mux, no guard branch inside the lockstep phases.
//
// Stream (depth-2, liveness-proven): during tile t the 4 phases stage
//   ph0: A0(t+1) -> other-buf A   (dead since last boundary)
//   ph1: A1(t+1) -> other-buf A
//   ph2: B0(t+2) -> cur-buf  B   (dead after ph0: all 8 B-frags read in ph0)
//   ph3: B1(t+2) -> cur-buf  B
// boundary: vmcnt(4) -> exactly B0/B1(t+2) stay in flight. Fused epilogue.
// ---------------------------------------------------------------------------
__global__ __launch_bounds__(512, 2) void lstm_gemm(
    const u16* __restrict__ xh, const u16* __restrict__ bt,
    const float* __restrict__ cprev,
    const float* __restrict__ ib, const float* __restrict__ fb,
    const float* __restrict__ ob, const float* __restrict__ cb,
    float* __restrict__ hout, float* __restrict__ cout) {
  __shared__ __align__(16) u16 lds[4 * 16384];   // 128 KiB

  int sx = threadIdx.x;
  // T1: bid%8 -> XCD; XCD k owns brows [4*(k&3),+4), bcols [8*(k>>2),+8)
  int bid = blockIdx.x;
  int xcd = bid & 7, lid = bid >> 3;
  int brow = ((xcd & 3) << 2) | (lid & 3);
  int bcol = ((xcd >> 2) << 3) | (lid >> 2);

  int w = sx >> 6, l = sx & 63;
  int wr = (w >> 2) << 7;              // 0 | 128 (WARPS_M = 2)
  int wc = (w & 3) << 6;               // 0,64,128,192 (WARPS_N = 4)
  int lrow = l & 15, q = l >> 4;
  int grow = brow << 8;

  // staging source pointers (per-lane global addr carries the k-chunk swizzle)
  int prow = sx >> 3;                                    // 0..63
  int koff = ((sx & 7) ^ (prow & 7)) << 3;               // swizzled k elems
  const u16* aS0 = xh + (size_t)(grow + prow) * KTOT + koff;          // rows 0-127
  const u16* aS1 = aS0 + (size_t)128 * KTOT;                          // rows 128-255
  const u16* bS0 = bt + (size_t)(bcol * 256 + prow) * KTOT + koff;
  const u16* bS1 = bS0 + (size_t)128 * KTOT;
  int sx8 = sx * 8;

  // fragment read offsets: physical chunk = logical ^ (row&7); row&7==lrow&7
  int aoff = (wr + lrow) << 6;
  int boff = (wc + lrow) << 6;
  int pc0 = (q ^ (lrow & 7)) << 3;          // k-step 0, quad q
  int pc1 = ((q + 4) ^ (lrow & 7)) << 3;    // k-step 1

  f32x4 acc[8][4] = {};
  bf16x8 af[2][2], bfr[4][2];

  // one half-tile stage: rows rb..rb+63 and rb+64..rb+127 (two 16B DMAs/lane)
#define STG(P_, K_, D_)                                                       \
  gl_lds16((P_) + (K_), &lds[(D_) + sx8]);                                    \
  gl_lds16((P_) + (size_t)64 * KTOT + (K_), &lds[(D_) + 4096 + sx8]);

  // prologue: tile0 {B0,B1,A0,A1} + tile1 {B0,B1}; wait tile0, B(1) flying
  STG(bS0, 0, B0B)
  STG(bS1, 0, B0B + 8192)
  STG(aS0, 0, A0B)
  STG(aS1, 0, A0B + 8192)
  STG(bS0, 64, B1B)
  STG(bS1, 64, B1B + 8192)
  asm volatile("s_waitcnt vmcnt(4)");
  __builtin_amdgcn_s_barrier();
  __builtin_amdgcn_sched_barrier(0);

#define RDA(AB_, i, pc) (*(const bf16x8*)&lds[(AB_) + aoff + (i) * 1024 + (pc)])
#define RDB(BB_, j, pc) (*(const bf16x8*)&lds[(BB_) + boff + (j) * 1024 + (pc)])

// one phase: ds-read subtile || stage stmt -> bar -> lgkm(0) -> setprio(1)
// -> 16 MFMA -> setprio(0). Caller adds the post-phase barrier.
#define DO_PHASE(K_, AB_, BB_, STG_STMT_)                                     \
  {                                                                           \
    af[0][0] = RDA(AB_, 2 * (K_), pc0);                                       \
    af[0][1] = RDA(AB_, 2 * (K_), pc1);                                       \
    af[1][0] = RDA(AB_, 2 * (K_) + 1, pc0);                                   \
    af[1][1] = RDA(AB_, 2 * (K_) + 1, pc1);                                   \
    if ((K_) == 0) {                                                          \
      bfr[0][0] = RDB(BB_, 0, pc0); bfr[0][1] = RDB(BB_, 0, pc1);             \
      bfr[1][0] = RDB(BB_, 1, pc0); bfr[1][1] = RDB(BB_, 1, pc1);             \
      bfr[2][0] = RDB(BB_, 2, pc0); bfr[2][1] = RDB(BB_, 2, pc1);             \
      bfr[3][0] = RDB(BB_, 3, pc0); bfr[3][1] = RDB(BB_, 3, pc1);             \
    }                                                                         \
    STG_STMT_                                                                 \
    __builtin_amdgcn_s_barrier();                                             \
    asm volatile("s_waitcnt lgkmcnt(0)");                                     \
    __builtin_amdgcn_sched_barrier(0);                                        \
    __builtin_amdgcn_s_setprio(1);                                            \
    _Pragma("unroll") for (int s2 = 0; s2 < 2; ++s2) {                        \
      _Pragma("unroll") for (int j = 0; j < 4; ++j) {                         \
        acc[2 * (K_)][j] = __builtin_amdgcn_mfma_f32_16x16x32_bf16(           \
            af[0][s2], bfr[j][s2], acc[2 * (K_)][j], 0, 0, 0);                \
        acc[2 * (K_) + 1][j] = __builtin_amdgcn_mfma_f32_16x16x32_bf16(       \
            af[1][s2], bfr[j][s2], acc[2 * (K_) + 1][j], 0, 0, 0);            \
      }                                                                       \
    }                                                                         \
    __builtin_amdgcn_s_setprio(0);                                            \
    __builtin_amdgcn_sched_barrier(0);                                        \
  }

#define BAR() __builtin_amdgcn_s_barrier();
#define BOUND(N_)                                                             \
  asm volatile("s_waitcnt vmcnt(" #N_ ")");                                   \
  __builtin_amdgcn_sched_barrier(0);                                          \
  __builtin_amdgcn_s_barrier();

  // main loop: 15 pairs = tiles 0..29, all with the full stage stream
  for (int tp = 0; tp < 15; ++tp) {
    int t = 2 * tp;
    int kA = (t + 1) << 6;       // A-stage k-offset (elems)
    int kB = (t + 2) << 6;       // B-stage k-offset
    int kA2 = kB;                // odd body A-stage
    int kB2 = (t + 3) << 6;      // odd body B-stage
    // even tile t: read buf0, stage A(t+1)->buf1.A, B(t+2)->buf0.B
    DO_PHASE(0, A0B, B0B, STG(aS0, kA, A1B))
    BAR()
    DO_PHASE(1, A0B, B0B, STG(aS1, kA, A1B + 8192))
    BAR()
    DO_PHASE(2, A0B, B0B, STG(bS0, kB, B0B))
    BAR()
    DO_PHASE(3, A0B, B0B, STG(bS1, kB, B0B + 8192))
    BOUND(4)
    // odd tile t+1: read buf1, stage A(t+2)->buf0.A, B(t+3)->buf1.B
    DO_PHASE(0, A1B, B1B, STG(aS0, kA2, A0B))
    BAR()
    DO_PHASE(1, A1B, B1B, STG(aS1, kA2, A0B + 8192))
    BAR()
    DO_PHASE(2, A1B, B1B, STG(bS0, kB2, B1B))
    BAR()
    DO_PHASE(3, A1B, B1B, STG(bS1, kB2, B1B + 8192))
    BOUND(4)
  }

  // tail: tile 30 (buf0) stages only A(31); tile 31 (buf1) stages nothing
  {
    const int kA = 31 << 6;
    DO_PHASE(0, A0B, B0B, STG(aS0, kA, A1B))
    BAR()
    DO_PHASE(1, A0B, B0B, STG(aS1, kA, A1B + 8192))
    BAR()
    DO_PHASE(2, A0B, B0B, )
    BAR()
    DO_PHASE(3, A0B, B0B, )
    BOUND(0)
    DO_PHASE(0, A1B, B1B, )
    BAR()
    DO_PHASE(1, A1B, B1B, )
    BAR()
    DO_PHASE(2, A1B, B1B, )
    BAR()
    DO_PHASE(3, A1B, B1B, )
  }
#undef DO_PHASE
#undef RDA
#undef RDB
#undef STG
#undef BAR
#undef BOUND

  // Epilogue: n-frag j = gate (i,f,o,c) for hidden cols of sub-block sb.
  int sb = (bcol << 2) + (w & 3);
  int hcol = (sb << 4) + lrow;
  float bi = ib[hcol];
  float bff = fb[hcol];
  float bo = ob[hcol];
  float bc = cb[hcol];

#pragma unroll
  for (int i = 0; i < 8; ++i) {
    int row0 = grow + wr + i * 16 + q * 4;
#pragma unroll
    for (int r = 0; r < 4; ++r) {
      size_t idx = (size_t)(row0 + r) * HID + hcol;
      float gi = sigmoid_fast(acc[i][0][r] + bi);
      float gf = sigmoid_fast(acc[i][1][r] + bff);
      float go = sigmoid_fast(acc[i][2][r] + bo);
      float gc = tanh_fast(acc[i][3][r] + bc);
      float cp = cprev[idx];
      float cv = gf * cp + gi * gc;
      hout[idx] = go * tanh_fast(cv);
      cout[idx] = cv;
    }
  }
}

extern "C" void kernel_launch(void* const* d_in, const int* in_sizes, int n_in,
                              void* d_out, int out_size, void* d_ws, size_t ws_size,
                              hipStream_t stream) {
  const float* x   = (const float*)d_in[0];
  const float* hp  = (const float*)d_in[1];
  const float* cp  = (const float*)d_in[2];
  const float* igx = (const float*)d_in[3];
  const float* igu = (const float*)d_in[4];
  const float* ib  = (const float*)d_in[5];
  const float* fgx = (const float*)d_in[6];
  const float* fgu = (const float*)d_in[7];
  const float* fb  = (const float*)d_in[8];
  const float* ogx = (const float*)d_in[9];
  const float* ogu = (const float*)d_in[10];
  const float* ob  = (const float*)d_in[11];
  const float* cgx = (const float*)d_in[12];
  const float* cgu = (const float*)d_in[13];
  const float* cb  = (const float*)d_in[14];

  u16* bt = (u16*)d_ws;                         // [4096][2048] bf16 = 16 MiB
  u16* xh = bt + (size_t)4096 * 2048;           // [4096][2048] bf16 = 16 MiB
  float* hout = (float*)d_out;
  float* cout = hout + (size_t)BATCH * HID;

  prep_all<<<6144, 256, 0, stream>>>(x, hp, igx, fgx, ogx, cgx,
                                     igu, fgu, ogu, cgu, xh, bt);
  lstm_gemm<<<256, 512, 0, stream>>>(xh, bt, cp, ib, fb, ob, cb,
                                     hout, cout);
}

// Round 5
// 205.605 us; speedup vs baseline: 1.0013x; 1.0013x over previous
//
#include <hip/hip_runtime.h>
#include <hip/hip_bf16.h>

typedef unsigned short u16;
typedef unsigned int u32;
typedef short bf16x8 __attribute__((ext_vector_type(8)));
typedef float f32x4 __attribute__((ext_vector_type(4)));
typedef u16 u16x8 __attribute__((ext_vector_type(8)));

#define HID 1024
#define BATCH 4096
#define KTOT 2048       // concat K: [x | h_prev]
#define NT 32           // K tiles of 64
// LDS element-index region bases: [A buf0 | B buf0 | A buf1 | B buf1]
#define A0B 0
#define B0B 16384
#define A1B 32768
#define B1B 49152

__device__ __forceinline__ u16 f2bf(float f) {
  u32 v = __builtin_bit_cast(u32, f);
  u32 r = (v + 0x7fffu + ((v >> 16) & 1u)) >> 16;  // round-nearest-even
  return (u16)r;
}
__device__ __forceinline__ float sigmoid_fast(float x) {
  return 1.0f / (1.0f + __expf(-x));
}
__device__ __forceinline__ float tanh_fast(float x) {
  return 2.0f * sigmoid_fast(2.0f * x) - 1.0f;
}
__device__ __forceinline__ void gl_lds16(const void* g, void* l) {
  __builtin_amdgcn_global_load_lds(
      (const __attribute__((address_space(1))) u32*)g,
      (__attribute__((address_space(3))) u32*)l, 16, 0, 0);
}

// ---------------------------------------------------------------------------
// prep_all: fused prep. Blocks [0,4096) build xh (bf16 [B][2048]); blocks
// [4096,6144) build Bt[n'][k] (bf16, gate-interleaved n') via LDS transpose.
// ---------------------------------------------------------------------------
__global__ __launch_bounds__(256) void prep_all(
    const float* __restrict__ x, const float* __restrict__ hp,
    const float* __restrict__ igx, const float* __restrict__ fgx,
    const float* __restrict__ ogx, const float* __restrict__ cgx,
    const float* __restrict__ igu, const float* __restrict__ fgu,
    const float* __restrict__ ogu, const float* __restrict__ cgu,
    u16* __restrict__ xh, u16* __restrict__ bt) {
  __shared__ u16 lds[64 * 66];
  if (blockIdx.x < 4096) {
    int c = blockIdx.x * 256 + threadIdx.x;  // chunk id, 8 elems each
    int row = c >> 8;
    int col0 = (c & 255) << 3;
    const float* src = (col0 < 1024)
                           ? (x + (size_t)row * 1024 + col0)
                           : (hp + (size_t)row * 1024 + (col0 - 1024));
    f32x4 a = *(const f32x4*)(src);
    f32x4 b = *(const f32x4*)(src + 4);
    u16x8 v;
#pragma unroll
    for (int j = 0; j < 4; ++j) { v[j] = f2bf(a[j]); v[j + 4] = f2bf(b[j]); }
    *(u16x8*)(xh + (size_t)row * KTOT + col0) = v;
    return;
  }
  // ---- weight transpose: n' = (h/16)*64 + g*16 + (h%16), k = which*1024+ksrc
  const float* srcs[8] = {igx, fgx, ogx, cgx, igu, fgu, ogu, cgu};
  int bid = blockIdx.x - 4096;
  int m = bid >> 8;            // matrix 0..7
  int tile = bid & 255;        // 64x64 tile
  int th = tile & 15, tk = tile >> 4;
  int h0 = th << 6, k0 = tk << 6;
  int g = m & 3, which = m >> 2;
  const float* W = srcs[m] + (size_t)k0 * HID + h0;

  int t = threadIdx.x;
  int r1 = t >> 4;
  int c1 = (t & 15) << 2;
#pragma unroll
  for (int p = 0; p < 4; ++p) {
    int row = (p << 4) + r1;
    f32x4 v = *(const f32x4*)(W + (size_t)row * HID + c1);
    u32 p0 = (u32)f2bf(v[0]) | ((u32)f2bf(v[1]) << 16);
    u32 p1 = (u32)f2bf(v[2]) | ((u32)f2bf(v[3]) << 16);
    u32* d = (u32*)&lds[row * 66 + c1];
    d[0] = p0;
    d[1] = p1;
  }
  __syncthreads();
  int nl = t >> 2;
  int kc = t & 3;
  int row_np = ((h0 >> 4) << 6) + ((nl >> 4) << 6) + (g << 4) + (nl & 15);
  size_t dst = (size_t)row_np * KTOT + (size_t)which * 1024 + k0;
  u16x8 a2, b2;
#pragma unroll
  for (int j = 0; j < 8; ++j) {
    a2[j] = lds[(kc * 8 + j) * 66 + nl];
    b2[j] = lds[(kc * 8 + 32 + j) * 66 + nl];
  }
  *(u16x8*)(&bt[dst + kc * 8]) = a2;
  *(u16x8*)(&bt[dst + kc * 8 + 32]) = b2;
}

// ---------------------------------------------------------------------------
// lstm_gemm: 256x256 tile, 8 waves (2Mx4N), BK=64, 8-phase schedule, counted
// vmcnt, setprio, XOR k-chunk swizzle via pre-swizzled global source
// (conflicts=0), T1 XCD block swizzle, 128 KiB LDS dbuf.
//
// NEW (R5): fragment-read software pipeline. Phase p's MFMA covers phase
// p+1's ds_reads (afP/afQ register ping-pong); ALL 8 B-frag reads for tile
// t+1 are prefetched during ph3 of tile t (bfP/bfQ tile-parity ping-pong).
// Safety: vmcnt(6) at ph2-end + barrier => every wave's B(t+1) DMAs (issued
// 1.5 tiles ago) have landed before any wave's ph3 prefetch reads them.
// Only 4 A-reads/tile remain exposed (post-boundary). Stage stream (per
// tile t): ph0 A0(t+1)->other.A, ph1 A1(t+1)->other.A, ph2 B0(t+2)->cur.B,
// ph3 B1(t+2)->cur.B; boundary vmcnt(4). Fused LSTM epilogue.
// ---------------------------------------------------------------------------
__global__ __launch_bounds__(512, 2) void lstm_gemm(
    const u16* __restrict__ xh, const u16* __restrict__ bt,
    const float* __restrict__ cprev,
    const float* __restrict__ ib, const float* __restrict__ fb,
    const float* __restrict__ ob, const float* __restrict__ cb,
    float* __restrict__ hout, float* __restrict__ cout) {
  __shared__ __align__(16) u16 lds[4 * 16384];   // 128 KiB

  int sx = threadIdx.x;
  // T1: bid%8 -> XCD; XCD k owns brows [4*(k&3),+4), bcols [8*(k>>2),+8)
  int bid = blockIdx.x;
  int xcd = bid & 7, lid = bid >> 3;
  int brow = ((xcd & 3) << 2) | (lid & 3);
  int bcol = ((xcd >> 2) << 3) | (lid >> 2);

  int w = sx >> 6, l = sx & 63;
  int wr = (w >> 2) << 7;              // 0 | 128 (WARPS_M = 2)
  int wc = (w & 3) << 6;               // 0,64,128,192 (WARPS_N = 4)
  int lrow = l & 15, q = l >> 4;
  int grow = brow << 8;

  // staging source pointers (per-lane global addr carries the k-chunk swizzle)
  int prow = sx >> 3;                                    // 0..63
  int koff = ((sx & 7) ^ (prow & 7)) << 3;               // swizzled k elems
  const u16* aS0 = xh + (size_t)(grow + prow) * KTOT + koff;   // rows 0-127
  const u16* aS1 = aS0 + (size_t)128 * KTOT;                   // rows 128-255
  const u16* bS0 = bt + (size_t)(bcol * 256 + prow) * KTOT + koff;
  const u16* bS1 = bS0 + (size_t)128 * KTOT;
  int sx8 = sx * 8;

  // fragment read offsets: physical chunk = logical ^ (row&7); row&7==lrow&7
  int aoff = (wr + lrow) << 6;
  int boff = (wc + lrow) << 6;
  int pc0 = (q ^ (lrow & 7)) << 3;          // k-step 0, quad q
  int pc1 = ((q + 4) ^ (lrow & 7)) << 3;    // k-step 1

  f32x4 acc[8][4] = {};
  bf16x8 afP[2][2], afQ[2][2];   // A frags, phase ping-pong
  bf16x8 bfP[4][2], bfQ[4][2];   // B frags, tile-parity ping-pong

#define STG(P_, K_, D_)                                                       \
  gl_lds16((P_) + (K_), &lds[(D_) + sx8]);                                    \
  gl_lds16((P_) + (size_t)64 * KTOT + (K_), &lds[(D_) + 4096 + sx8]);

#define RDA(AB_, i, pc) (*(const bf16x8*)&lds[(AB_) + aoff + (i) * 1024 + (pc)])
#define RDB(BB_, j, pc) (*(const bf16x8*)&lds[(BB_) + boff + (j) * 1024 + (pc)])

#define ISS_A(D_, AB_, I0_)                                                   \
  D_[0][0] = RDA(AB_, I0_, pc0);                                              \
  D_[0][1] = RDA(AB_, I0_, pc1);                                              \
  D_[1][0] = RDA(AB_, (I0_) + 1, pc0);                                        \
  D_[1][1] = RDA(AB_, (I0_) + 1, pc1);

#define ISS_B(D_, BB_)                                                        \
  D_[0][0] = RDB(BB_, 0, pc0); D_[0][1] = RDB(BB_, 0, pc1);                   \
  D_[1][0] = RDB(BB_, 1, pc0); D_[1][1] = RDB(BB_, 1, pc1);                   \
  D_[2][0] = RDB(BB_, 2, pc0); D_[2][1] = RDB(BB_, 2, pc1);                   \
  D_[3][0] = RDB(BB_, 3, pc0); D_[3][1] = RDB(BB_, 3, pc1);

#define MFMA16(K_, AF_, BF_)                                                  \
  __builtin_amdgcn_s_setprio(1);                                              \
  _Pragma("unroll") for (int s2 = 0; s2 < 2; ++s2) {                          \
    _Pragma("unroll") for (int j = 0; j < 4; ++j) {                           \
      acc[2 * (K_)][j] = __builtin_amdgcn_mfma_f32_16x16x32_bf16(             \
          AF_[0][s2], BF_[j][s2], acc[2 * (K_)][j], 0, 0, 0);                 \
      acc[2 * (K_) + 1][j] = __builtin_amdgcn_mfma_f32_16x16x32_bf16(         \
          AF_[1][s2], BF_[j][s2], acc[2 * (K_) + 1][j], 0, 0, 0);             \
    }                                                                         \
  }                                                                           \
  __builtin_amdgcn_s_setprio(0);                                              \
  __builtin_amdgcn_sched_barrier(0);

// one phase: stage -> bar -> lgkm(0) -> issue next-phase reads -> MFMA
#define DO_PHASE(K_, AF_, BF_, ISSUE_, STG_)                                  \
  {                                                                           \
    STG_                                                                      \
    __builtin_amdgcn_s_barrier();                                             \
    asm volatile("s_waitcnt lgkmcnt(0)");                                     \
    __builtin_amdgcn_sched_barrier(0);                                        \
    ISSUE_                                                                    \
    __builtin_amdgcn_sched_barrier(0);                                        \
    MFMA16(K_, AF_, BF_)                                                      \
  }

#define BAR() __builtin_amdgcn_s_barrier();
#define VMW(N_)                                                               \
  asm volatile("s_waitcnt vmcnt(" #N_ ")");                                   \
  __builtin_amdgcn_sched_barrier(0);

  // prologue: B(0), A(0), B(1); wait B(0)+A(0); preload frags for tile 0
  STG(bS0, 0, B0B)
  STG(bS1, 0, B0B + 8192)
  STG(aS0, 0, A0B)
  STG(aS1, 0, A0B + 8192)
  STG(bS0, 64, B1B)
  STG(bS1, 64, B1B + 8192)
  VMW(4)
  __builtin_amdgcn_s_barrier();
  ISS_B(bfP, B0B)
  ISS_A(afP, A0B, 0)
  __builtin_amdgcn_sched_barrier(0);

  // even tile: cur A0B/B0B (bfP); prefetch B(t+1) from B1B into bfQ
#define TILE_EVEN(kA_, kB_)                                                   \
  DO_PHASE(0, afP, bfP, ISS_A(afQ, A0B, 2), STG(aS0, kA_, A1B))               \
  BAR()                                                                       \
  DO_PHASE(1, afQ, bfP, ISS_A(afP, A0B, 4), STG(aS1, kA_, A1B + 8192))        \
  BAR()                                                                       \
  DO_PHASE(2, afP, bfP, ISS_A(afQ, A0B, 6), STG(bS0, kB_, B0B))               \
  VMW(6) BAR()                                                                \
  DO_PHASE(3, afQ, bfP, ISS_B(bfQ, B1B), STG(bS1, kB_, B0B + 8192))           \
  VMW(4) BAR()                                                                \
  ISS_A(afP, A1B, 0)                                                          \
  __builtin_amdgcn_sched_barrier(0);

  // odd tile: cur A1B/B1B (bfQ); prefetch B(t+1) from B0B into bfP
#define TILE_ODD(kA_, kB_)                                                    \
  DO_PHASE(0, afP, bfQ, ISS_A(afQ, A1B, 2), STG(aS0, kA_, A0B))               \
  BAR()                                                                       \
  DO_PHASE(1, afQ, bfQ, ISS_A(afP, A1B, 4), STG(aS1, kA_, A0B + 8192))        \
  BAR()                                                                       \
  DO_PHASE(2, afP, bfQ, ISS_A(afQ, A1B, 6), STG(bS0, kB_, B1B))               \
  VMW(6) BAR()                                                                \
  DO_PHASE(3, afQ, bfQ, ISS_B(bfP, B0B), STG(bS1, kB_, B1B + 8192))           \
  VMW(4) BAR()                                                                \
  ISS_A(afP, A0B, 0)                                                          \
  __builtin_amdgcn_sched_barrier(0);

  // tiles 0..29 in pairs
  for (int tp = 0; tp < 15; ++tp) {
    int t = 2 * tp;
    int kA = (t + 1) << 6;
    int kB = (t + 2) << 6;
    int kA2 = (t + 2) << 6;
    int kB2 = (t + 3) << 6;
    TILE_EVEN(kA, kB)
    TILE_ODD(kA2, kB2)
  }

  // tile 30 (even): stages only A(31); ph2-end vmcnt(4) (B(31) landed),
  // boundary vmcnt(0) (A(31) landed). tile 31 (odd): pure drain.
  {
    const int kA = 31 << 6;
    DO_PHASE(0, afP, bfP, ISS_A(afQ, A0B, 2), STG(aS0, kA, A1B))
    BAR()
    DO_PHASE(1, afQ, bfP, ISS_A(afP, A0B, 4), STG(aS1, kA, A1B + 8192))
    BAR()
    DO_PHASE(2, afP, bfP, ISS_A(afQ, A0B, 6), )
    VMW(4) BAR()
    DO_PHASE(3, afQ, bfP, ISS_B(bfQ, B1B), )
    VMW(0) BAR()
    ISS_A(afP, A1B, 0)
    __builtin_amdgcn_sched_barrier(0);
    DO_PHASE(0, afP, bfQ, ISS_A(afQ, A1B, 2), )
    BAR()
    DO_PHASE(1, afQ, bfQ, ISS_A(afP, A1B, 4), )
    BAR()
    DO_PHASE(2, afP, bfQ, ISS_A(afQ, A1B, 6), )
    BAR()
    DO_PHASE(3, afQ, bfQ, , )
  }
#undef DO_PHASE
#undef MFMA16
#undef ISS_A
#undef ISS_B
#undef RDA
#undef RDB
#undef STG
#undef BAR
#undef VMW
#undef TILE_EVEN
#undef TILE_ODD

  // Epilogue: n-frag j = gate (i,f,o,c) for hidden cols of sub-block sb.
  int sb = (bcol << 2) + (w & 3);
  int hcol = (sb << 4) + lrow;
  float bi = ib[hcol];
  float bff = fb[hcol];
  float bo = ob[hcol];
  float bc = cb[hcol];

#pragma unroll
  for (int i = 0; i < 8; ++i) {
    int row0 = grow + wr + i * 16 + q * 4;
#pragma unroll
    for (int r = 0; r < 4; ++r) {
      size_t idx = (size_t)(row0 + r) * HID + hcol;
      float gi = sigmoid_fast(acc[i][0][r] + bi);
      float gf = sigmoid_fast(acc[i][1][r] + bff);
      float go = sigmoid_fast(acc[i][2][r] + bo);
      float gc = tanh_fast(acc[i][3][r] + bc);
      float cp = cprev[idx];
      float cv = gf * cp + gi * gc;
      hout[idx] = go * tanh_fast(cv);
      cout[idx] = cv;
    }
  }
}

extern "C" void kernel_launch(void* const* d_in, const int* in_sizes, int n_in,
                              void* d_out, int out_size, void* d_ws, size_t ws_size,
                              hipStream_t stream) {
  const float* x   = (const float*)d_in[0];
  const float* hp  = (const float*)d_in[1];
  const float* cp  = (const float*)d_in[2];
  const float* igx = (const float*)d_in[3];
  const float* igu = (const float*)d_in[4];
  const float* ib  = (const float*)d_in[5];
  const float* fgx = (const float*)d_in[6];
  const float* fgu = (const float*)d_in[7];
  const float* fb  = (const float*)d_in[8];
  const float* ogx = (const float*)d_in[9];
  const float* ogu = (const float*)d_in[10];
  const float* ob  = (const float*)d_in[11];
  const float* cgx = (const float*)d_in[12];
  const float* cgu = (const float*)d_in[13];
  const float* cb  = (const float*)d_in[14];

  u16* bt = (u16*)d_ws;                         // [4096][2048] bf16 = 16 MiB
  u16* xh = bt + (size_t)4096 * 2048;           // [4096][2048] bf16 = 16 MiB
  float* hout = (float*)d_out;
  float* cout = hout + (size_t)BATCH * HID;

  prep_all<<<6144, 256, 0, stream>>>(x, hp, igx, fgx, ogx, cgx,
                                     igu, fgu, ogu, cgu, xh, bt);
  lstm_gemm<<<256, 512, 0, stream>>>(xh, bt, cp, ib, fb, ob, cb,
                                     hout, cout);
}

// Round 6
// 205.157 us; speedup vs baseline: 1.0035x; 1.0022x over previous
//
#include <hip/hip_runtime.h>
#include <hip/hip_bf16.h>

typedef unsigned short u16;
typedef unsigned int u32;
typedef short bf16x8 __attribute__((ext_vector_type(8)));
typedef float f32x4 __attribute__((ext_vector_type(4)));
typedef u16 u16x8 __attribute__((ext_vector_type(8)));

#define HID 1024
#define BATCH 4096
#define KTOT 2048       // concat K: [x | h_prev]
#define NT 32           // K tiles of 64
// LDS element-index region bases: [A buf0 | A buf1 | B buf0 | B buf1]
#define A0B 0
#define A1B 16384
#define B0B 32768
#define B1B 49152

__device__ __forceinline__ u16 f2bf(float f) {
  u32 v = __builtin_bit_cast(u32, f);
  u32 r = (v + 0x7fffu + ((v >> 16) & 1u)) >> 16;  // round-nearest-even
  return (u16)r;
}
__device__ __forceinline__ float sigmoid_fast(float x) {
  return 1.0f / (1.0f + __expf(-x));
}
__device__ __forceinline__ float tanh_fast(float x) {
  return 2.0f * sigmoid_fast(2.0f * x) - 1.0f;
}
__device__ __forceinline__ void gl_lds16(const void* g, void* l) {
  __builtin_amdgcn_global_load_lds(
      (const __attribute__((address_space(1))) u32*)g,
      (__attribute__((address_space(3))) u32*)l, 16, 0, 0);
}

// ---------------------------------------------------------------------------
// prep_all: fused prep. Blocks [0,4096) build xh (bf16 [B][2048]); blocks
// [4096,6144) build Bt[n'][k] (bf16, gate-interleaved n') via LDS transpose.
// ---------------------------------------------------------------------------
__global__ __launch_bounds__(256) void prep_all(
    const float* __restrict__ x, const float* __restrict__ hp,
    const float* __restrict__ igx, const float* __restrict__ fgx,
    const float* __restrict__ ogx, const float* __restrict__ cgx,
    const float* __restrict__ igu, const float* __restrict__ fgu,
    const float* __restrict__ ogu, const float* __restrict__ cgu,
    u16* __restrict__ xh, u16* __restrict__ bt) {
  __shared__ u16 lds[64 * 66];
  if (blockIdx.x < 4096) {
    int c = blockIdx.x * 256 + threadIdx.x;  // chunk id, 8 elems each
    int row = c >> 8;
    int col0 = (c & 255) << 3;
    const float* src = (col0 < 1024)
                           ? (x + (size_t)row * 1024 + col0)
                           : (hp + (size_t)row * 1024 + (col0 - 1024));
    f32x4 a = *(const f32x4*)(src);
    f32x4 b = *(const f32x4*)(src + 4);
    u16x8 v;
#pragma unroll
    for (int j = 0; j < 4; ++j) { v[j] = f2bf(a[j]); v[j + 4] = f2bf(b[j]); }
    *(u16x8*)(xh + (size_t)row * KTOT + col0) = v;
    return;
  }
  // ---- weight transpose: n' = (h/16)*64 + g*16 + (h%16), k = which*1024+ksrc
  const float* srcs[8] = {igx, fgx, ogx, cgx, igu, fgu, ogu, cgu};
  int bid = blockIdx.x - 4096;
  int m = bid >> 8;            // matrix 0..7
  int tile = bid & 255;        // 64x64 tile
  int th = tile & 15, tk = tile >> 4;
  int h0 = th << 6, k0 = tk << 6;
  int g = m & 3, which = m >> 2;
  const float* W = srcs[m] + (size_t)k0 * HID + h0;

  int t = threadIdx.x;
  int r1 = t >> 4;
  int c1 = (t & 15) << 2;
#pragma unroll
  for (int p = 0; p < 4; ++p) {
    int row = (p << 4) + r1;
    f32x4 v = *(const f32x4*)(W + (size_t)row * HID + c1);
    u32 p0 = (u32)f2bf(v[0]) | ((u32)f2bf(v[1]) << 16);
    u32 p1 = (u32)f2bf(v[2]) | ((u32)f2bf(v[3]) << 16);
    u32* d = (u32*)&lds[row * 66 + c1];
    d[0] = p0;
    d[1] = p1;
  }
  __syncthreads();
  int nl = t >> 2;
  int kc = t & 3;
  int row_np = ((h0 >> 4) << 6) + ((nl >> 4) << 6) + (g << 4) + (nl & 15);
  size_t dst = (size_t)row_np * KTOT + (size_t)which * 1024 + k0;
  u16x8 a2, b2;
#pragma unroll
  for (int j = 0; j < 8; ++j) {
    a2[j] = lds[(kc * 8 + j) * 66 + nl];
    b2[j] = lds[(kc * 8 + 32 + j) * 66 + nl];
  }
  *(u16x8*)(&bt[dst + kc * 8]) = a2;
  *(u16x8*)(&bt[dst + kc * 8 + 32]) = b2;
}

// ---------------------------------------------------------------------------
// lstm_gemm (R6): 256x256 tile, 8 waves (2Mx4N), BK=64, ONE barrier per
// K-tile. Liveness: tile t reads only buf(t&1); all stages write buf(~t&1),
// whose last reader finished before the PREVIOUS __syncthreads(). So no
// mid-tile barriers are needed — waves free-run through the tile, and
// cross-wave phase skew overlaps the LDS pipe (ds_read + DMA-writes) with
// the matrix pipe. Stage-DMAs for tile t+1 issue at the TOP of tile t
// (~2400 cyc flight >> 900 cyc HBM latency), so the __syncthreads() vmcnt
// drain at the boundary is nearly free. Interior is compiler-scheduled
// (partial lgkmcnt); only pin = sched_barrier(0) after the stage block so
// DMAs can't sink. XOR k-chunk swizzle via pre-swizzled global source
// (conflicts=0), T1 XCD block swizzle, 128 KiB LDS dbuf, fused epilogue.
// ---------------------------------------------------------------------------
__global__ __launch_bounds__(512, 2) void lstm_gemm(
    const u16* __restrict__ xh, const u16* __restrict__ bt,
    const float* __restrict__ cprev,
    const float* __restrict__ ib, const float* __restrict__ fb,
    const float* __restrict__ ob, const float* __restrict__ cb,
    float* __restrict__ hout, float* __restrict__ cout) {
  __shared__ __align__(16) u16 lds[4 * 16384];   // 128 KiB

  int sx = threadIdx.x;
  // T1: bid%8 -> XCD; XCD k owns brows [4*(k&3),+4), bcols [8*(k>>2),+8)
  int bid = blockIdx.x;
  int xcd = bid & 7, lid = bid >> 3;
  int brow = ((xcd & 3) << 2) | (lid & 3);
  int bcol = ((xcd >> 2) << 3) | (lid >> 2);

  int w = sx >> 6, l = sx & 63;
  int wr = (w >> 2) << 7;              // 0 | 128 (WARPS_M = 2)
  int wc = (w & 3) << 6;               // 0,64,128,192 (WARPS_N = 4)
  int lrow = l & 15, q = l >> 4;
  int grow = brow << 8;

  // staging source pointers (per-lane global addr carries the k-chunk swizzle)
  int prow = sx >> 3;                                    // 0..63
  int koff = ((sx & 7) ^ (prow & 7)) << 3;               // swizzled k elems
  const u16* aS0 = xh + (size_t)(grow + prow) * KTOT + koff;   // rows 0-127
  const u16* aS1 = aS0 + (size_t)128 * KTOT;                   // rows 128-255
  const u16* bS0 = bt + (size_t)(bcol * 256 + prow) * KTOT + koff;
  const u16* bS1 = bS0 + (size_t)128 * KTOT;
  int sx8 = sx * 8;

  // fragment read offsets: physical chunk = logical ^ (row&7); row&7==lrow&7
  int aoff = (wr + lrow) << 6;
  int boff = (wc + lrow) << 6;
  int pc0 = (q ^ (lrow & 7)) << 3;          // k-step 0, quad q
  int pc1 = ((q + 4) ^ (lrow & 7)) << 3;    // k-step 1

  f32x4 acc[8][4] = {};
  bf16x8 afP[2][2], afQ[2][2];   // A frag ping-pong (in-wave)
  bf16x8 bfr[4][2];              // B frags, read once per tile

#define STG(P_, K_, D_)                                                       \
  gl_lds16((P_) + (K_), &lds[(D_) + sx8]);                                    \
  gl_lds16((P_) + (size_t)64 * KTOT + (K_), &lds[(D_) + 4096 + sx8]);

#define RDA(AB_, i, pc) (*(const bf16x8*)&lds[(AB_) + aoff + (i) * 1024 + (pc)])
#define RDB(BB_, j, pc) (*(const bf16x8*)&lds[(BB_) + boff + (j) * 1024 + (pc)])

#define ISS_A(D_, AB_, I0_)                                                   \
  D_[0][0] = RDA(AB_, I0_, pc0);                                              \
  D_[0][1] = RDA(AB_, I0_, pc1);                                              \
  D_[1][0] = RDA(AB_, (I0_) + 1, pc0);                                        \
  D_[1][1] = RDA(AB_, (I0_) + 1, pc1);

#define ISS_B(D_, BB_)                                                        \
  D_[0][0] = RDB(BB_, 0, pc0); D_[0][1] = RDB(BB_, 0, pc1);                   \
  D_[1][0] = RDB(BB_, 1, pc0); D_[1][1] = RDB(BB_, 1, pc1);                   \
  D_[2][0] = RDB(BB_, 2, pc0); D_[2][1] = RDB(BB_, 2, pc1);                   \
  D_[3][0] = RDB(BB_, 3, pc0); D_[3][1] = RDB(BB_, 3, pc1);

#define MFMA16(K_, AF_)                                                       \
  __builtin_amdgcn_s_setprio(1);                                              \
  _Pragma("unroll") for (int s2 = 0; s2 < 2; ++s2) {                          \
    _Pragma("unroll") for (int j = 0; j < 4; ++j) {                           \
      acc[2 * (K_)][j] = __builtin_amdgcn_mfma_f32_16x16x32_bf16(             \
          AF_[0][s2], bfr[j][s2], acc[2 * (K_)][j], 0, 0, 0);                 \
      acc[2 * (K_) + 1][j] = __builtin_amdgcn_mfma_f32_16x16x32_bf16(         \
          AF_[1][s2], bfr[j][s2], acc[2 * (K_) + 1][j], 0, 0, 0);             \
    }                                                                         \
  }                                                                           \
  __builtin_amdgcn_s_setprio(0);

  // interior: 24 ds_reads + 64 MFMAs, compiler-scheduled (partial lgkmcnt)
#define INTERIOR(AC_, BC_)                                                    \
  ISS_B(bfr, (BC_))                                                           \
  ISS_A(afP, (AC_), 0)                                                        \
  MFMA16(0, afP)                                                              \
  ISS_A(afQ, (AC_), 2)                                                        \
  MFMA16(1, afQ)                                                              \
  ISS_A(afP, (AC_), 4)                                                        \
  MFMA16(2, afP)                                                              \
  ISS_A(afQ, (AC_), 6)                                                        \
  MFMA16(3, afQ)

  // full tile: stage next tile's A+B at top (max DMA flight), then interior
#define TILE(AC_, BC_, KN_, AD_, BD_)                                         \
  {                                                                           \
    STG(aS0, (KN_), (AD_))                                                    \
    STG(aS1, (KN_), (AD_) + 8192)                                             \
    STG(bS0, (KN_), (BD_))                                                    \
    STG(bS1, (KN_), (BD_) + 8192)                                             \
    __builtin_amdgcn_sched_barrier(0);                                        \
    INTERIOR(AC_, BC_)                                                        \
  }

  // prologue: tile 0's A+B; __syncthreads drains vmcnt(0) + barriers
  STG(aS0, 0, A0B)
  STG(aS1, 0, A0B + 8192)
  STG(bS0, 0, B0B)
  STG(bS1, 0, B0B + 8192)
  __syncthreads();

  // tiles 0..29: uniform bodies, stage tile t+1 into the other buffer
  for (int tp = 0; tp < 15; ++tp) {
    int k1 = (2 * tp + 1) << 6;
    int k2 = (2 * tp + 2) << 6;
    TILE(A0B, B0B, k1, A1B, B1B)
    __syncthreads();
    TILE(A1B, B1B, k2, A0B, B0B)
    __syncthreads();
  }
  // tile 30: stage tile 31; tile 31: no stage
  TILE(A0B, B0B, 31 << 6, A1B, B1B)
  __syncthreads();
  INTERIOR(A1B, B1B)

#undef TILE
#undef INTERIOR
#undef MFMA16
#undef ISS_A
#undef ISS_B
#undef RDA
#undef RDB
#undef STG

  // Epilogue: n-frag j = gate (i,f,o,c) for hidden cols of sub-block sb.
  int sb = (bcol << 2) + (w & 3);
  int hcol = (sb << 4) + lrow;
  float bi = ib[hcol];
  float bff = fb[hcol];
  float bo = ob[hcol];
  float bc = cb[hcol];

#pragma unroll
  for (int i = 0; i < 8; ++i) {
    int row0 = grow + wr + i * 16 + q * 4;
#pragma unroll
    for (int r = 0; r < 4; ++r) {
      size_t idx = (size_t)(row0 + r) * HID + hcol;
      float gi = sigmoid_fast(acc[i][0][r] + bi);
      float gf = sigmoid_fast(acc[i][1][r] + bff);
      float go = sigmoid_fast(acc[i][2][r] + bo);
      float gc = tanh_fast(acc[i][3][r] + bc);
      float cp = cprev[idx];
      float cv = gf * cp + gi * gc;
      hout[idx] = go * tanh_fast(cv);
      cout[idx] = cv;
    }
  }
}

extern "C" void kernel_launch(void* const* d_in, const int* in_sizes, int n_in,
                              void* d_out, int out_size, void* d_ws, size_t ws_size,
                              hipStream_t stream) {
  const float* x   = (const float*)d_in[0];
  const float* hp  = (const float*)d_in[1];
  const float* cp  = (const float*)d_in[2];
  const float* igx = (const float*)d_in[3];
  const float* igu = (const float*)d_in[4];
  const float* ib  = (const float*)d_in[5];
  const float* fgx = (const float*)d_in[6];
  const float* fgu = (const float*)d_in[7];
  const float* fb  = (const float*)d_in[8];
  const float* ogx = (const float*)d_in[9];
  const float* ogu = (const float*)d_in[10];
  const float* ob  = (const float*)d_in[11];
  const float* cgx = (const float*)d_in[12];
  const float* cgu = (const float*)d_in[13];
  const float* cb  = (const float*)d_in[14];

  u16* bt = (u16*)d_ws;                         // [4096][2048] bf16 = 16 MiB
  u16* xh = bt + (size_t)4096 * 2048;           // [4096][2048] bf16 = 16 MiB
  float* hout = (float*)d_out;
  float* cout = hout + (size_t)BATCH * HID;

  prep_all<<<6144, 256, 0, stream>>>(x, hp, igx, fgx, ogx, cgx,
                                     igu, fgu, ogu, cgu, xh, bt);
  lstm_gemm<<<256, 512, 0, stream>>>(xh, bt, cp, ib, fb, ob, cb,
                                     hout, cout);
}